// Round 12
// baseline (225.726 us; speedup 1.0000x reference)
//
#include <hip/hip_runtime.h>
#include <hip/hip_bf16.h>
#include <hip/hip_fp16.h>

typedef _Float16 half8 __attribute__((ext_vector_type(8)));
typedef float floatx4 __attribute__((ext_vector_type(4)));
typedef unsigned short u16;
typedef unsigned int u32;
typedef unsigned long long u64;

#define LEAKY 0.2f
#define MASKV -9.0e15f

// ---------------- Kernel A: h_ds[b][d] = (mean of 150 rows) @ wd ----------------
__global__ __launch_bounds__(256) void k_hds(const float* __restrict__ hl,
                                             const float* __restrict__ ht,
                                             const float* __restrict__ ie,
                                             const float* __restrict__ wd,
                                             float* __restrict__ hds) {
  int b = blockIdx.x, tid = threadIdx.x;
  int d = tid & 127, hh = tid >> 7;
  __shared__ float pa_[2][128];
  __shared__ float ml[128];
  __shared__ float pb_[2][128];
  const size_t base = (size_t)b * 50 * 128 + d;
  float acc = 0.f;
  for (int r = hh * 25; r < hh * 25 + 25; ++r) {
    size_t o = base + (size_t)r * 128;
    acc += hl[o] + ht[o] + ie[o];
  }
  pa_[hh][d] = acc;
  __syncthreads();
  if (hh == 0) ml[d] = (pa_[0][d] + pa_[1][d]) * (1.0f / 150.0f);
  __syncthreads();
  float o = 0.f;
  for (int k = hh * 64; k < hh * 64 + 64; ++k) o = fmaf(ml[k], wd[k * 128 + d], o);
  pb_[hh][d] = o;
  __syncthreads();
  if (hh == 0) hds[b * 128 + d] = pb_[0][d] + pb_[1][d];
}

// ---------------- Kernel B: s[w][b][i], h16[b][i][d], h16T[b][d][i] ----------------
__global__ __launch_bounds__(256) void k_prep(const float* __restrict__ h,
                                              const float* __restrict__ hds,
                                              const float* __restrict__ a0,
                                              const float* __restrict__ a1,
                                              const float* __restrict__ a2,
                                              const float* __restrict__ a3,
                                              float* __restrict__ s,
                                              u16* __restrict__ h16,
                                              u16* __restrict__ h16T) {
  int b = blockIdx.x >> 3, i0 = (blockIdx.x & 7) * 64;
  int tid = threadIdx.x, w = tid >> 6, l = tid & 63;
  __shared__ u16 tile[64][130];
  int d0 = 2 * l;
  float2 hd2 = *(const float2*)(hds + b * 128 + d0);
  float2 av0 = *(const float2*)(a0 + d0);
  float2 av1 = *(const float2*)(a1 + d0);
  float2 av2 = *(const float2*)(a2 + d0);
  float2 av3 = *(const float2*)(a3 + d0);
  for (int rr = 0; rr < 16; ++rr) {
    int il = rr * 4 + w;
    size_t row = (size_t)b * 512 + i0 + il;
    float2 hv = *(const float2*)(h + row * 128 + d0);
    _Float16 f0 = (_Float16)hv.x, f1 = (_Float16)hv.y;
    u16 u0 = __builtin_bit_cast(u16, f0), u1 = __builtin_bit_cast(u16, f1);
    tile[il][d0] = u0;
    tile[il][d0 + 1] = u1;
    *(u32*)(h16 + row * 128 + d0) = (u32)u0 | ((u32)u1 << 16);
    float t0 = hv.x * hd2.x, t1 = hv.y * hd2.y;
    float p0 = t0 * av0.x + t1 * av0.y;
    float p1 = t0 * av1.x + t1 * av1.y;
    float p2 = t0 * av2.x + t1 * av2.y;
    float p3 = t0 * av3.x + t1 * av3.y;
    for (int off = 32; off >= 1; off >>= 1) {
      p0 += __shfl_xor(p0, off);
      p1 += __shfl_xor(p1, off);
      p2 += __shfl_xor(p2, off);
      p3 += __shfl_xor(p3, off);
    }
    if (l < 4) {
      float pw = (l == 0) ? p0 : (l == 1) ? p1 : (l == 2) ? p2 : p3;
      s[((size_t)l * 64 + b) * 512 + i0 + il] = pw;
    }
  }
  __syncthreads();
  int d = tid >> 1, hf = tid & 1;
  u32 wds[16];
#pragma unroll
  for (int k = 0; k < 16; ++k) {
    u32 lo = tile[32 * hf + 2 * k][d];
    u32 hi = tile[32 * hf + 2 * k + 1][d];
    wds[k] = lo | (hi << 16);
  }
  uint4* dst = (uint4*)(h16T + ((size_t)b * 128 + d) * 512 + i0 + 32 * hf);
  dst[0] = make_uint4(wds[0], wds[1], wds[2], wds[3]);
  dst[1] = make_uint4(wds[4], wds[5], wds[6], wds[7]);
  dst[2] = make_uint4(wds[8], wds[9], wds[10], wds[11]);
  dst[3] = make_uint4(wds[12], wds[13], wds[14], wds[15]);
}

// ---------------- Kernel C: independent-wave fused attention ----------------
// Block = 4 waves, 16-row i-tile; wave jq owns j-quarter (128 j's = 2 t-iters).
// Register diet for 3 waves/SIMD: head-PAIR QK passes (qk[2][4] reused twice),
// codes + s loads transient inside the t-loop.
__global__ __launch_bounds__(256, 3) void k_attn(const u16* __restrict__ h16,
                                                 const u16* __restrict__ h16T,
                                                 const float* __restrict__ s,
                                                 const int* __restrict__ adj,
                                                 const float* __restrict__ a0,
                                                 const float* __restrict__ a1,
                                                 const float* __restrict__ a2,
                                                 const float* __restrict__ a3,
                                                 float* __restrict__ out) {
  int bid = blockIdx.x;
  int wg = (bid & 7) * 256 + (bid >> 3);  // XCD swizzle (2048 % 8 == 0, bijective)
  int b = wg >> 5, i0r = (wg & 31) * 16;
  int tid = threadIdx.x, jq = tid >> 6, l = tid & 63;
  int l15 = l & 15, l4 = l >> 4;

  __shared__ u16 a16[4][128];        // a vectors, f16
  __shared__ u16 pbuf[4][16][72];    // per-wave P relayout
  __shared__ float mrg[3][16][132];  // quarter-merge pv (jq=1..3)
  __shared__ float mml[3][16][2];    // quarter-merge m,l

  if (tid < 128) {
    a16[0][tid] = __builtin_bit_cast(u16, (_Float16)a0[tid]);
    a16[1][tid] = __builtin_bit_cast(u16, (_Float16)a1[tid]);
    a16[2][tid] = __builtin_bit_cast(u16, (_Float16)a2[tid]);
    a16[3][tid] = __builtin_bit_cast(u16, (_Float16)a3[tid]);
  }
  __syncthreads();

  const size_t hb16 = (size_t)b * 512 * 128;
  const size_t hTb = (size_t)b * 128 * 512;

  // A-side h fragments (iteration-invariant): row = l15, k = ks*32+8*l4+e
  half8 hf[4];
#pragma unroll
  for (int ks = 0; ks < 4; ++ks)
    hf[ks] = *(const half8*)(h16 + hb16 + (size_t)(i0r + l15) * 128 + ks * 32 + 8 * l4);

  float m[4], lsum[4];
#pragma unroll
  for (int e = 0; e < 4; ++e) { m[e] = MASKV; lsum[e] = 0.f; }
  floatx4 pv[8];
#pragma unroll
  for (int dt = 0; dt < 8; ++dt) pv[dt] = (floatx4){0.f, 0.f, 0.f, 0.f};

  for (int t = 0; t < 2; ++t) {
    int j0 = jq * 128 + t * 64;

    // ---- packed head-bit codes for this tile (issued early; hides under QK) ----
    // ct[e]: bit (4*hd+C) = (adj[b][i0r+4*l4+e][j0 + 16*C + l15] == hd+1)
    u32 ct[4];
#pragma unroll
    for (int e = 0; e < 4; ++e) {
      u32 v = 0;
      const int* ap = adj + ((size_t)(b * 512 + i0r + 4 * l4 + e)) * 512 + j0 + l15;
#pragma unroll
      for (int C = 0; C < 4; ++C) {
        int av = ap[16 * C];
        if (av > 0) v |= (1u << (4 * (av - 1) + C));
      }
      ct[e] = v;
    }

    float x[4][4];
#pragma unroll
    for (int C = 0; C < 4; ++C)
#pragma unroll
      for (int e = 0; e < 4; ++e) x[C][e] = MASKV;

    // ---- two head-pair passes: qk[2][4] reused ----
#pragma unroll
    for (int hp = 0; hp < 2; ++hp) {
      floatx4 qk[2][4];
#pragma unroll
      for (int hh = 0; hh < 2; ++hh)
#pragma unroll
        for (int C = 0; C < 4; ++C) qk[hh][C] = (floatx4){0.f, 0.f, 0.f, 0.f};
#pragma unroll
      for (int ks = 0; ks < 4; ++ks) {
        half8 kf[4];
#pragma unroll
        for (int C = 0; C < 4; ++C)
          kf[C] = *(const half8*)(h16 + hb16 + (size_t)(j0 + 16 * C + l15) * 128 + ks * 32 + 8 * l4);
#pragma unroll
        for (int hh = 0; hh < 2; ++hh) {
          half8 af = *(const half8*)&a16[2 * hp + hh][ks * 32 + 8 * l4];
          half8 q = hf[ks] * af;
#pragma unroll
          for (int C = 0; C < 4; ++C)
            qk[hh][C] = __builtin_amdgcn_mfma_f32_16x16x32_f16(q, kf[C], qk[hh][C], 0, 0, 0);
        }
      }
      // select for these two heads (s loads transient, L2-hot)
#pragma unroll
      for (int hh = 0; hh < 2; ++hh) {
        int hd = 2 * hp + hh;
        const float* sh = s + ((size_t)hd * 64 + b) * 512;
        float sjh[4], sih[4];
#pragma unroll
        for (int C = 0; C < 4; ++C) sjh[C] = sh[j0 + 16 * C + l15];
#pragma unroll
        for (int e = 0; e < 4; ++e) sih[e] = sh[i0r + 4 * l4 + e];
#pragma unroll
        for (int e = 0; e < 4; ++e) {
#pragma unroll
          for (int C = 0; C < 4; ++C) {
            if ((ct[e] >> (4 * hd + C)) & 1) {
              float v = qk[hh][C][e] + sih[e] + sjh[C];
              x[C][e] = (v > 0.f) ? v : LEAKY * v;
            }
          }
        }
      }
    }

    // ---- online softmax (rows r = 4*l4+e, reduce across 16 l15 lanes) ----
#pragma unroll
    for (int e = 0; e < 4; ++e) {
      float tmax = fmaxf(fmaxf(x[0][e], x[1][e]), fmaxf(x[2][e], x[3][e]));
      tmax = fmaxf(tmax, __shfl_xor(tmax, 1));
      tmax = fmaxf(tmax, __shfl_xor(tmax, 2));
      tmax = fmaxf(tmax, __shfl_xor(tmax, 4));
      tmax = fmaxf(tmax, __shfl_xor(tmax, 8));
      float mn = fmaxf(m[e], tmax);
      float sc = __expf(m[e] - mn);
      float p0 = __expf(x[0][e] - mn);
      float p1 = __expf(x[1][e] - mn);
      float p2 = __expf(x[2][e] - mn);
      float p3 = __expf(x[3][e] - mn);
      float ls = (p0 + p1) + (p2 + p3);
      ls += __shfl_xor(ls, 1);
      ls += __shfl_xor(ls, 2);
      ls += __shfl_xor(ls, 4);
      ls += __shfl_xor(ls, 8);
      lsum[e] = lsum[e] * sc + ls;
      m[e] = mn;
#pragma unroll
      for (int dt = 0; dt < 8; ++dt) pv[dt][e] *= sc;
      int r = 4 * l4 + e;
      pbuf[jq][r][0 + l15] = __builtin_bit_cast(u16, (_Float16)p0);
      pbuf[jq][r][16 + l15] = __builtin_bit_cast(u16, (_Float16)p1);
      pbuf[jq][r][32 + l15] = __builtin_bit_cast(u16, (_Float16)p2);
      pbuf[jq][r][48 + l15] = __builtin_bit_cast(u16, (_Float16)p3);
    }

    asm volatile("s_waitcnt lgkmcnt(0)" ::: "memory");
    __builtin_amdgcn_sched_barrier(0);

    // ---- PV: A = P (row=l15), B = V^T from h16T ----
#pragma unroll
    for (int ks2 = 0; ks2 < 2; ++ks2) {
      half8 pa = *(const half8*)((const char*)&pbuf[jq][0][0] + l15 * 144 + ks2 * 64 + l4 * 16);
#pragma unroll
      for (int dt = 0; dt < 8; ++dt) {
        half8 vb = *(const half8*)(h16T + hTb + (size_t)(16 * dt + l15) * 512 + j0 + ks2 * 32 + 8 * l4);
        pv[dt] = __builtin_amdgcn_mfma_f32_16x16x32_f16(pa, vb, pv[dt], 0, 0, 0);
      }
    }
  }

  // ---- 4-way quarter merge ----
  if (jq != 0) {
#pragma unroll
    for (int dt = 0; dt < 8; ++dt)
#pragma unroll
      for (int e = 0; e < 4; ++e)
        mrg[jq - 1][4 * l4 + e][16 * dt + l15] = pv[dt][e];
    if (l15 == 0) {
#pragma unroll
      for (int e = 0; e < 4; ++e) {
        mml[jq - 1][4 * l4 + e][0] = m[e];
        mml[jq - 1][4 * l4 + e][1] = lsum[e];
      }
    }
  }
  __syncthreads();
  if (jq == 0) {
    float wq[4][3], inv[4];
#pragma unroll
    for (int e = 0; e < 4; ++e) {
      int r = 4 * l4 + e;
      float M = m[e];
#pragma unroll
      for (int q = 0; q < 3; ++q) M = fmaxf(M, mml[q][r][0]);
      float w0 = __expf(m[e] - M);
      float L = lsum[e] * w0;
#pragma unroll
      for (int q = 0; q < 3; ++q) {
        wq[e][q] = __expf(mml[q][r][0] - M);
        L += mml[q][r][1] * wq[e][q];
      }
      inv[e] = 1.0f / L;
      wq[e][0] *= inv[e]; wq[e][1] *= inv[e]; wq[e][2] *= inv[e];
      inv[e] *= w0;  // weight for own pv
    }
#pragma unroll
    for (int dt = 0; dt < 8; ++dt)
#pragma unroll
      for (int e = 0; e < 4; ++e) {
        int r = 4 * l4 + e;
        float o = pv[dt][e] * inv[e];
#pragma unroll
        for (int q = 0; q < 3; ++q) o += mrg[q][r][16 * dt + l15] * wq[e][q];
        out[((size_t)b * 512 + i0r + r) * 128 + 16 * dt + l15] = o;
      }
  }
}

extern "C" void kernel_launch(void* const* d_in, const int* in_sizes, int n_in,
                              void* d_out, int out_size, void* d_ws, size_t ws_size,
                              hipStream_t stream) {
  const float* hl = (const float*)d_in[0];
  const float* ht = (const float*)d_in[1];
  const float* ie = (const float*)d_in[2];
  const float* h  = (const float*)d_in[3];
  const int* adj  = (const int*)d_in[4];
  const float* wd = (const float*)d_in[5];
  const float* a0 = (const float*)d_in[6];
  const float* a1 = (const float*)d_in[7];
  const float* a2 = (const float*)d_in[8];
  const float* a3 = (const float*)d_in[9];

  // ws layout (~16.6 MB)
  float* hds  = (float*)d_ws;                   // 32 KB
  float* s    = (float*)((char*)d_ws + 32768);  // [4][64][512] = 512 KB
  u16* h16    = (u16*)((char*)d_ws + 557056);   // 8 MB
  u16* h16T   = (u16*)((char*)d_ws + 8945664);  // 8 MB
  float* o    = (float*)d_out;

  k_hds<<<64, 256, 0, stream>>>(hl, ht, ie, wd, hds);
  k_prep<<<512, 256, 0, stream>>>(h, hds, a0, a1, a2, a3, s, h16, h16T);
  k_attn<<<2048, 256, 0, stream>>>(h16, h16T, s, adj, a0, a1, a2, a3, o);
}

// Round 13
// 115.301 us; speedup vs baseline: 1.9577x; 1.9577x over previous
//
#include <hip/hip_runtime.h>
#include <hip/hip_bf16.h>
#include <hip/hip_fp16.h>

typedef _Float16 half8 __attribute__((ext_vector_type(8)));
typedef float floatx4 __attribute__((ext_vector_type(4)));
typedef unsigned short u16;
typedef unsigned int u32;
typedef unsigned long long u64;

#define LEAKY 0.2f
#define MASKV -9.0e15f

// ---------------- Kernel A: h_ds[b][d] = (mean of 150 rows) @ wd ----------------
__global__ __launch_bounds__(256) void k_hds(const float* __restrict__ hl,
                                             const float* __restrict__ ht,
                                             const float* __restrict__ ie,
                                             const float* __restrict__ wd,
                                             float* __restrict__ hds) {
  int b = blockIdx.x, tid = threadIdx.x;
  int d = tid & 127, hh = tid >> 7;
  __shared__ float pa_[2][128];
  __shared__ float ml[128];
  __shared__ float pb_[2][128];
  const size_t base = (size_t)b * 50 * 128 + d;
  float acc = 0.f;
  for (int r = hh * 25; r < hh * 25 + 25; ++r) {
    size_t o = base + (size_t)r * 128;
    acc += hl[o] + ht[o] + ie[o];
  }
  pa_[hh][d] = acc;
  __syncthreads();
  if (hh == 0) ml[d] = (pa_[0][d] + pa_[1][d]) * (1.0f / 150.0f);
  __syncthreads();
  float o = 0.f;
  for (int k = hh * 64; k < hh * 64 + 64; ++k) o = fmaf(ml[k], wd[k * 128 + d], o);
  pb_[hh][d] = o;
  __syncthreads();
  if (hh == 0) hds[b * 128 + d] = pb_[0][d] + pb_[1][d];
}

// ---------------- Kernel B: s[w][b][i], h16[b][i][d], h16T[b][d][i] ----------------
__global__ __launch_bounds__(256) void k_prep(const float* __restrict__ h,
                                              const float* __restrict__ hds,
                                              const float* __restrict__ a0,
                                              const float* __restrict__ a1,
                                              const float* __restrict__ a2,
                                              const float* __restrict__ a3,
                                              float* __restrict__ s,
                                              u16* __restrict__ h16,
                                              u16* __restrict__ h16T) {
  int b = blockIdx.x >> 3, i0 = (blockIdx.x & 7) * 64;
  int tid = threadIdx.x, w = tid >> 6, l = tid & 63;
  __shared__ u16 tile[64][130];
  int d0 = 2 * l;
  float2 hd2 = *(const float2*)(hds + b * 128 + d0);
  float2 av0 = *(const float2*)(a0 + d0);
  float2 av1 = *(const float2*)(a1 + d0);
  float2 av2 = *(const float2*)(a2 + d0);
  float2 av3 = *(const float2*)(a3 + d0);
  for (int rr = 0; rr < 16; ++rr) {
    int il = rr * 4 + w;
    size_t row = (size_t)b * 512 + i0 + il;
    float2 hv = *(const float2*)(h + row * 128 + d0);
    _Float16 f0 = (_Float16)hv.x, f1 = (_Float16)hv.y;
    u16 u0 = __builtin_bit_cast(u16, f0), u1 = __builtin_bit_cast(u16, f1);
    tile[il][d0] = u0;
    tile[il][d0 + 1] = u1;
    *(u32*)(h16 + row * 128 + d0) = (u32)u0 | ((u32)u1 << 16);
    float t0 = hv.x * hd2.x, t1 = hv.y * hd2.y;
    float p0 = t0 * av0.x + t1 * av0.y;
    float p1 = t0 * av1.x + t1 * av1.y;
    float p2 = t0 * av2.x + t1 * av2.y;
    float p3 = t0 * av3.x + t1 * av3.y;
    for (int off = 32; off >= 1; off >>= 1) {
      p0 += __shfl_xor(p0, off);
      p1 += __shfl_xor(p1, off);
      p2 += __shfl_xor(p2, off);
      p3 += __shfl_xor(p3, off);
    }
    if (l < 4) {
      float pw = (l == 0) ? p0 : (l == 1) ? p1 : (l == 2) ? p2 : p3;
      s[((size_t)l * 64 + b) * 512 + i0 + il] = pw;
    }
  }
  __syncthreads();
  int d = tid >> 1, hf = tid & 1;
  u32 wds[16];
#pragma unroll
  for (int k = 0; k < 16; ++k) {
    u32 lo = tile[32 * hf + 2 * k][d];
    u32 hi = tile[32 * hf + 2 * k + 1][d];
    wds[k] = lo | (hi << 16);
  }
  uint4* dst = (uint4*)(h16T + ((size_t)b * 128 + d) * 512 + i0 + 32 * hf);
  dst[0] = make_uint4(wds[0], wds[1], wds[2], wds[3]);
  dst[1] = make_uint4(wds[4], wds[5], wds[6], wds[7]);
  dst[2] = make_uint4(wds[8], wds[9], wds[10], wds[11]);
  dst[3] = make_uint4(wds[12], wds[13], wds[14], wds[15]);
}

// ---------------- Kernel C: independent-wave fused attention ----------------
// Block = 4 waves, 16-row i-tile; wave jq owns j-quarter (128 j's = 2 t-iters).
// Two-phase t-iter: ALL loads issued up front (ct + all 16 K-frags), then one
// long MFMA burst (4 heads share kfa). V-frags prefetched before softmax.
// __launch_bounds__(256,2): 256 unified regs/wave -> 2 waves/SIMD, no spill.
__global__ __launch_bounds__(256, 2) void k_attn(const u16* __restrict__ h16,
                                                 const u16* __restrict__ h16T,
                                                 const float* __restrict__ s,
                                                 const int* __restrict__ adj,
                                                 const float* __restrict__ a0,
                                                 const float* __restrict__ a1,
                                                 const float* __restrict__ a2,
                                                 const float* __restrict__ a3,
                                                 float* __restrict__ out) {
  int bid = blockIdx.x;
  int wg = (bid & 7) * 256 + (bid >> 3);  // XCD swizzle (2048 % 8 == 0, bijective)
  int b = wg >> 5, i0r = (wg & 31) * 16;
  int tid = threadIdx.x, jq = tid >> 6, l = tid & 63;
  int l15 = l & 15, l4 = l >> 4;

  __shared__ u16 a16[4][128];        // a vectors, f16
  __shared__ u16 pbuf[4][16][72];    // per-wave P relayout
  __shared__ float mrg[3][16][132];  // quarter-merge pv (jq=1..3)
  __shared__ float mml[3][16][2];    // quarter-merge m,l

  if (tid < 128) {
    a16[0][tid] = __builtin_bit_cast(u16, (_Float16)a0[tid]);
    a16[1][tid] = __builtin_bit_cast(u16, (_Float16)a1[tid]);
    a16[2][tid] = __builtin_bit_cast(u16, (_Float16)a2[tid]);
    a16[3][tid] = __builtin_bit_cast(u16, (_Float16)a3[tid]);
  }
  __syncthreads();

  const size_t hb16 = (size_t)b * 512 * 128;
  const size_t hTb = (size_t)b * 128 * 512;

  // A-side h fragments (iteration-invariant): row = l15, k = ks*32+8*l4+e
  half8 hf[4];
#pragma unroll
  for (int ks = 0; ks < 4; ++ks)
    hf[ks] = *(const half8*)(h16 + hb16 + (size_t)(i0r + l15) * 128 + ks * 32 + 8 * l4);

  float m[4], lsum[4];
#pragma unroll
  for (int e = 0; e < 4; ++e) { m[e] = MASKV; lsum[e] = 0.f; }
  floatx4 pv[8];
#pragma unroll
  for (int dt = 0; dt < 8; ++dt) pv[dt] = (floatx4){0.f, 0.f, 0.f, 0.f};

  for (int t = 0; t < 2; ++t) {
    int j0 = jq * 128 + t * 64;

    // ---- phase 1: issue ALL independent loads for this tile ----
    // packed head-bit codes from adj (16 × 4B, HBM-cold -> longest latency, first)
    u32 ct[4];
#pragma unroll
    for (int e = 0; e < 4; ++e) {
      u32 v = 0;
      const int* ap = adj + ((size_t)(b * 512 + i0r + 4 * l4 + e)) * 512 + j0 + l15;
#pragma unroll
      for (int C = 0; C < 4; ++C) {
        int av = ap[16 * C];
        if (av > 0) v |= (1u << (4 * (av - 1) + C));
      }
      ct[e] = v;
    }
    // all 16 K fragments (shared by all 4 heads)
    half8 kfa[16];
#pragma unroll
    for (int ks = 0; ks < 4; ++ks)
#pragma unroll
      for (int C = 0; C < 4; ++C)
        kfa[ks * 4 + C] = *(const half8*)(h16 + hb16 + (size_t)(j0 + 16 * C + l15) * 128 + ks * 32 + 8 * l4);

    float x[4][4];
#pragma unroll
    for (int C = 0; C < 4; ++C)
#pragma unroll
      for (int e = 0; e < 4; ++e) x[C][e] = MASKV;

    // ---- phase 2: 4 sequential head passes, pure MFMA from registers ----
#pragma unroll
    for (int hd = 0; hd < 4; ++hd) {
      const float* sh = s + ((size_t)hd * 64 + b) * 512;
      float sjh[4], sih[4];
#pragma unroll
      for (int C = 0; C < 4; ++C) sjh[C] = sh[j0 + 16 * C + l15];
#pragma unroll
      for (int e = 0; e < 4; ++e) sih[e] = sh[i0r + 4 * l4 + e];

      floatx4 qk[4];
#pragma unroll
      for (int C = 0; C < 4; ++C) qk[C] = (floatx4){0.f, 0.f, 0.f, 0.f};
#pragma unroll
      for (int ks = 0; ks < 4; ++ks) {
        half8 af = *(const half8*)&a16[hd][ks * 32 + 8 * l4];
        half8 q = hf[ks] * af;
#pragma unroll
        for (int C = 0; C < 4; ++C)
          qk[C] = __builtin_amdgcn_mfma_f32_16x16x32_f16(q, kfa[ks * 4 + C], qk[C], 0, 0, 0);
      }
#pragma unroll
      for (int e = 0; e < 4; ++e) {
#pragma unroll
        for (int C = 0; C < 4; ++C) {
          if ((ct[e] >> (4 * hd + C)) & 1) {
            float v = qk[C][e] + sih[e] + sjh[C];
            x[C][e] = (v > 0.f) ? v : LEAKY * v;
          }
        }
      }
    }

    // ---- prefetch all 16 V fragments (independent of softmax) ----
    half8 vba[16];
#pragma unroll
    for (int ks2 = 0; ks2 < 2; ++ks2)
#pragma unroll
      for (int dt = 0; dt < 8; ++dt)
        vba[ks2 * 8 + dt] = *(const half8*)(h16T + hTb + (size_t)(16 * dt + l15) * 512 + j0 + ks2 * 32 + 8 * l4);

    // ---- online softmax (rows r = 4*l4+e, reduce across 16 l15 lanes) ----
#pragma unroll
    for (int e = 0; e < 4; ++e) {
      float tmax = fmaxf(fmaxf(x[0][e], x[1][e]), fmaxf(x[2][e], x[3][e]));
      tmax = fmaxf(tmax, __shfl_xor(tmax, 1));
      tmax = fmaxf(tmax, __shfl_xor(tmax, 2));
      tmax = fmaxf(tmax, __shfl_xor(tmax, 4));
      tmax = fmaxf(tmax, __shfl_xor(tmax, 8));
      float mn = fmaxf(m[e], tmax);
      float sc = __expf(m[e] - mn);
      float p0 = __expf(x[0][e] - mn);
      float p1 = __expf(x[1][e] - mn);
      float p2 = __expf(x[2][e] - mn);
      float p3 = __expf(x[3][e] - mn);
      float ls = (p0 + p1) + (p2 + p3);
      ls += __shfl_xor(ls, 1);
      ls += __shfl_xor(ls, 2);
      ls += __shfl_xor(ls, 4);
      ls += __shfl_xor(ls, 8);
      lsum[e] = lsum[e] * sc + ls;
      m[e] = mn;
#pragma unroll
      for (int dt = 0; dt < 8; ++dt) pv[dt][e] *= sc;
      int r = 4 * l4 + e;
      pbuf[jq][r][0 + l15] = __builtin_bit_cast(u16, (_Float16)p0);
      pbuf[jq][r][16 + l15] = __builtin_bit_cast(u16, (_Float16)p1);
      pbuf[jq][r][32 + l15] = __builtin_bit_cast(u16, (_Float16)p2);
      pbuf[jq][r][48 + l15] = __builtin_bit_cast(u16, (_Float16)p3);
    }

    asm volatile("s_waitcnt lgkmcnt(0)" ::: "memory");
    __builtin_amdgcn_sched_barrier(0);

    // ---- PV: A = P (row=l15), B = V^T (prefetched) ----
#pragma unroll
    for (int ks2 = 0; ks2 < 2; ++ks2) {
      half8 pa = *(const half8*)((const char*)&pbuf[jq][0][0] + l15 * 144 + ks2 * 64 + l4 * 16);
#pragma unroll
      for (int dt = 0; dt < 8; ++dt)
        pv[dt] = __builtin_amdgcn_mfma_f32_16x16x32_f16(pa, vba[ks2 * 8 + dt], pv[dt], 0, 0, 0);
    }
  }

  // ---- 4-way quarter merge ----
  if (jq != 0) {
#pragma unroll
    for (int dt = 0; dt < 8; ++dt)
#pragma unroll
      for (int e = 0; e < 4; ++e)
        mrg[jq - 1][4 * l4 + e][16 * dt + l15] = pv[dt][e];
    if (l15 == 0) {
#pragma unroll
      for (int e = 0; e < 4; ++e) {
        mml[jq - 1][4 * l4 + e][0] = m[e];
        mml[jq - 1][4 * l4 + e][1] = lsum[e];
      }
    }
  }
  __syncthreads();
  if (jq == 0) {
    float wq[4][3], inv[4];
#pragma unroll
    for (int e = 0; e < 4; ++e) {
      int r = 4 * l4 + e;
      float M = m[e];
#pragma unroll
      for (int q = 0; q < 3; ++q) M = fmaxf(M, mml[q][r][0]);
      float w0 = __expf(m[e] - M);
      float L = lsum[e] * w0;
#pragma unroll
      for (int q = 0; q < 3; ++q) {
        wq[e][q] = __expf(mml[q][r][0] - M);
        L += mml[q][r][1] * wq[e][q];
      }
      inv[e] = 1.0f / L;
      wq[e][0] *= inv[e]; wq[e][1] *= inv[e]; wq[e][2] *= inv[e];
      inv[e] *= w0;  // weight for own pv
    }
#pragma unroll
    for (int dt = 0; dt < 8; ++dt)
#pragma unroll
      for (int e = 0; e < 4; ++e) {
        int r = 4 * l4 + e;
        float o = pv[dt][e] * inv[e];
#pragma unroll
        for (int q = 0; q < 3; ++q) o += mrg[q][r][16 * dt + l15] * wq[e][q];
        out[((size_t)b * 512 + i0r + r) * 128 + 16 * dt + l15] = o;
      }
  }
}

extern "C" void kernel_launch(void* const* d_in, const int* in_sizes, int n_in,
                              void* d_out, int out_size, void* d_ws, size_t ws_size,
                              hipStream_t stream) {
  const float* hl = (const float*)d_in[0];
  const float* ht = (const float*)d_in[1];
  const float* ie = (const float*)d_in[2];
  const float* h  = (const float*)d_in[3];
  const int* adj  = (const int*)d_in[4];
  const float* wd = (const float*)d_in[5];
  const float* a0 = (const float*)d_in[6];
  const float* a1 = (const float*)d_in[7];
  const float* a2 = (const float*)d_in[8];
  const float* a3 = (const float*)d_in[9];

  // ws layout (~16.6 MB)
  float* hds  = (float*)d_ws;                   // 32 KB
  float* s    = (float*)((char*)d_ws + 32768);  // [4][64][512] = 512 KB
  u16* h16    = (u16*)((char*)d_ws + 557056);   // 8 MB
  u16* h16T   = (u16*)((char*)d_ws + 8945664);  // 8 MB
  float* o    = (float*)d_out;

  k_hds<<<64, 256, 0, stream>>>(hl, ht, ie, wd, hds);
  k_prep<<<512, 256, 0, stream>>>(h, hds, a0, a1, a2, a3, s, h16, h16T);
  k_attn<<<2048, 256, 0, stream>>>(h16, h16T, s, adj, a0, a1, a2, a3, o);
}

// Round 14
// 108.172 us; speedup vs baseline: 2.0867x; 1.0659x over previous
//
#include <hip/hip_runtime.h>
#include <hip/hip_bf16.h>
#include <hip/hip_fp16.h>

typedef _Float16 half8 __attribute__((ext_vector_type(8)));
typedef float floatx4 __attribute__((ext_vector_type(4)));
typedef unsigned short u16;
typedef unsigned int u32;
typedef unsigned long long u64;

#define LEAKY 0.2f
#define MASKV -9.0e15f

// ---------------- Kernel A: h_ds[b][d] = (mean of 150 rows) @ wd ----------------
__global__ __launch_bounds__(256) void k_hds(const float* __restrict__ hl,
                                             const float* __restrict__ ht,
                                             const float* __restrict__ ie,
                                             const float* __restrict__ wd,
                                             float* __restrict__ hds) {
  int b = blockIdx.x, tid = threadIdx.x;
  int d = tid & 127, hh = tid >> 7;
  __shared__ float pa_[2][128];
  __shared__ float ml[128];
  __shared__ float pb_[2][128];
  const size_t base = (size_t)b * 50 * 128 + d;
  float acc = 0.f;
  for (int r = hh * 25; r < hh * 25 + 25; ++r) {
    size_t o = base + (size_t)r * 128;
    acc += hl[o] + ht[o] + ie[o];
  }
  pa_[hh][d] = acc;
  __syncthreads();
  if (hh == 0) ml[d] = (pa_[0][d] + pa_[1][d]) * (1.0f / 150.0f);
  __syncthreads();
  float o = 0.f;
  for (int k = hh * 64; k < hh * 64 + 64; ++k) o = fmaf(ml[k], wd[k * 128 + d], o);
  pb_[hh][d] = o;
  __syncthreads();
  if (hh == 0) hds[b * 128 + d] = pb_[0][d] + pb_[1][d];
}

// ---------------- Kernel B: s[w][b][i], h16[b][i][d], h16T[b][d][i] ----------------
__global__ __launch_bounds__(256) void k_prep(const float* __restrict__ h,
                                              const float* __restrict__ hds,
                                              const float* __restrict__ a0,
                                              const float* __restrict__ a1,
                                              const float* __restrict__ a2,
                                              const float* __restrict__ a3,
                                              float* __restrict__ s,
                                              u16* __restrict__ h16,
                                              u16* __restrict__ h16T) {
  int b = blockIdx.x >> 3, i0 = (blockIdx.x & 7) * 64;
  int tid = threadIdx.x, w = tid >> 6, l = tid & 63;
  __shared__ u16 tile[64][130];
  int d0 = 2 * l;
  float2 hd2 = *(const float2*)(hds + b * 128 + d0);
  float2 av0 = *(const float2*)(a0 + d0);
  float2 av1 = *(const float2*)(a1 + d0);
  float2 av2 = *(const float2*)(a2 + d0);
  float2 av3 = *(const float2*)(a3 + d0);
  for (int rr = 0; rr < 16; ++rr) {
    int il = rr * 4 + w;
    size_t row = (size_t)b * 512 + i0 + il;
    float2 hv = *(const float2*)(h + row * 128 + d0);
    _Float16 f0 = (_Float16)hv.x, f1 = (_Float16)hv.y;
    u16 u0 = __builtin_bit_cast(u16, f0), u1 = __builtin_bit_cast(u16, f1);
    tile[il][d0] = u0;
    tile[il][d0 + 1] = u1;
    *(u32*)(h16 + row * 128 + d0) = (u32)u0 | ((u32)u1 << 16);
    float t0 = hv.x * hd2.x, t1 = hv.y * hd2.y;
    float p0 = t0 * av0.x + t1 * av0.y;
    float p1 = t0 * av1.x + t1 * av1.y;
    float p2 = t0 * av2.x + t1 * av2.y;
    float p3 = t0 * av3.x + t1 * av3.y;
    for (int off = 32; off >= 1; off >>= 1) {
      p0 += __shfl_xor(p0, off);
      p1 += __shfl_xor(p1, off);
      p2 += __shfl_xor(p2, off);
      p3 += __shfl_xor(p3, off);
    }
    if (l < 4) {
      float pw = (l == 0) ? p0 : (l == 1) ? p1 : (l == 2) ? p2 : p3;
      s[((size_t)l * 64 + b) * 512 + i0 + il] = pw;
    }
  }
  __syncthreads();
  int d = tid >> 1, hf = tid & 1;
  u32 wds[16];
#pragma unroll
  for (int k = 0; k < 16; ++k) {
    u32 lo = tile[32 * hf + 2 * k][d];
    u32 hi = tile[32 * hf + 2 * k + 1][d];
    wds[k] = lo | (hi << 16);
  }
  uint4* dst = (uint4*)(h16T + ((size_t)b * 128 + d) * 512 + i0 + 32 * hf);
  dst[0] = make_uint4(wds[0], wds[1], wds[2], wds[3]);
  dst[1] = make_uint4(wds[4], wds[5], wds[6], wds[7]);
  dst[2] = make_uint4(wds[8], wds[9], wds[10], wds[11]);
  dst[3] = make_uint4(wds[12], wds[13], wds[14], wds[15]);
}

// ---------------- Kernel C: independent-wave fused attention ----------------
// Block = 4 waves, 16-row i-tile; wave jq owns j-quarter (128 j's = 2 t-iters).
// R14: s staged in LDS (no per-iter L2 s-loads), adj codes hoisted to prologue,
// t-loop unrolled, setprio around MFMA bursts. __launch_bounds__(256,2).
__global__ __launch_bounds__(256, 2) void k_attn(const u16* __restrict__ h16,
                                                 const u16* __restrict__ h16T,
                                                 const float* __restrict__ s,
                                                 const int* __restrict__ adj,
                                                 const float* __restrict__ a0,
                                                 const float* __restrict__ a1,
                                                 const float* __restrict__ a2,
                                                 const float* __restrict__ a3,
                                                 float* __restrict__ out) {
  int bid = blockIdx.x;
  int wg = (bid & 7) * 256 + (bid >> 3);  // XCD swizzle (2048 % 8 == 0, bijective)
  int b = wg >> 5, i0r = (wg & 31) * 16;
  int tid = threadIdx.x, jq = tid >> 6, l = tid & 63;
  int l15 = l & 15, l4 = l >> 4;

  __shared__ u16 a16[4][128];        // a vectors, f16
  __shared__ float s_lds[4][512];    // per-head s row for this b (8 KB)
  __shared__ u16 pbuf[4][16][72];    // per-wave P relayout
  __shared__ float mrg[3][16][132];  // quarter-merge pv (jq=1..3)
  __shared__ float mml[3][16][2];    // quarter-merge m,l

  const size_t hb16 = (size_t)b * 512 * 128;
  const size_t hTb = (size_t)b * 128 * 512;

  // ---- prologue: issue HBM-cold adj loads first (both t-iters) ----
  u32 ct[2][4];
#pragma unroll
  for (int t = 0; t < 2; ++t)
#pragma unroll
    for (int e = 0; e < 4; ++e) {
      u32 v = 0;
      const int* ap = adj + ((size_t)(b * 512 + i0r + 4 * l4 + e)) * 512 + jq * 128 + t * 64 + l15;
#pragma unroll
      for (int C = 0; C < 4; ++C) {
        int av = ap[16 * C];
        if (av > 0) v |= (1u << (4 * (av - 1) + C));
      }
      ct[t][e] = v;
    }

  // A-side h fragments: row = l15, k = ks*32+8*l4+e
  half8 hf[4];
#pragma unroll
  for (int ks = 0; ks < 4; ++ks)
    hf[ks] = *(const half8*)(h16 + hb16 + (size_t)(i0r + l15) * 128 + ks * 32 + 8 * l4);

  // cooperative staging: a vectors (f16) + s rows (f32) into LDS
  if (tid < 128) {
    a16[0][tid] = __builtin_bit_cast(u16, (_Float16)a0[tid]);
    a16[1][tid] = __builtin_bit_cast(u16, (_Float16)a1[tid]);
    a16[2][tid] = __builtin_bit_cast(u16, (_Float16)a2[tid]);
    a16[3][tid] = __builtin_bit_cast(u16, (_Float16)a3[tid]);
  }
#pragma unroll
  for (int p = 0; p < 2; ++p) {
    int cid = p * 256 + tid;           // [0,512)
    int hd = cid >> 7, i4 = (cid & 127) * 4;
    *(float4*)&s_lds[hd][i4] = *(const float4*)(s + ((size_t)hd * 64 + b) * 512 + i4);
  }
  __syncthreads();

  // s_i per head (t-invariant, from LDS)
  float si[4][4];
#pragma unroll
  for (int hd = 0; hd < 4; ++hd)
#pragma unroll
    for (int e = 0; e < 4; ++e)
      si[hd][e] = s_lds[hd][i0r + 4 * l4 + e];

  float m[4], lsum[4];
#pragma unroll
  for (int e = 0; e < 4; ++e) { m[e] = MASKV; lsum[e] = 0.f; }
  floatx4 pv[8];
#pragma unroll
  for (int dt = 0; dt < 8; ++dt) pv[dt] = (floatx4){0.f, 0.f, 0.f, 0.f};

#pragma unroll
  for (int t = 0; t < 2; ++t) {
    int j0 = jq * 128 + t * 64;

    // ---- all 16 K fragments (shared by all 4 heads) ----
    half8 kfa[16];
#pragma unroll
    for (int ks = 0; ks < 4; ++ks)
#pragma unroll
      for (int C = 0; C < 4; ++C)
        kfa[ks * 4 + C] = *(const half8*)(h16 + hb16 + (size_t)(j0 + 16 * C + l15) * 128 + ks * 32 + 8 * l4);

    float x[4][4];
#pragma unroll
    for (int C = 0; C < 4; ++C)
#pragma unroll
      for (int e = 0; e < 4; ++e) x[C][e] = MASKV;

    // ---- 4 sequential head passes, MFMA from registers, s from LDS ----
#pragma unroll
    for (int hd = 0; hd < 4; ++hd) {
      float sjh[4];
#pragma unroll
      for (int C = 0; C < 4; ++C) sjh[C] = s_lds[hd][j0 + 16 * C + l15];

      floatx4 qk[4];
#pragma unroll
      for (int C = 0; C < 4; ++C) qk[C] = (floatx4){0.f, 0.f, 0.f, 0.f};
      __builtin_amdgcn_s_setprio(1);
#pragma unroll
      for (int ks = 0; ks < 4; ++ks) {
        half8 af = *(const half8*)&a16[hd][ks * 32 + 8 * l4];
        half8 q = hf[ks] * af;
#pragma unroll
        for (int C = 0; C < 4; ++C)
          qk[C] = __builtin_amdgcn_mfma_f32_16x16x32_f16(q, kfa[ks * 4 + C], qk[C], 0, 0, 0);
      }
      __builtin_amdgcn_s_setprio(0);
#pragma unroll
      for (int e = 0; e < 4; ++e) {
#pragma unroll
        for (int C = 0; C < 4; ++C) {
          if ((ct[t][e] >> (4 * hd + C)) & 1) {
            float v = qk[C][e] + si[hd][e] + sjh[C];
            x[C][e] = (v > 0.f) ? v : LEAKY * v;
          }
        }
      }
    }

    // ---- prefetch all 16 V fragments (independent of softmax) ----
    half8 vba[16];
#pragma unroll
    for (int ks2 = 0; ks2 < 2; ++ks2)
#pragma unroll
      for (int dt = 0; dt < 8; ++dt)
        vba[ks2 * 8 + dt] = *(const half8*)(h16T + hTb + (size_t)(16 * dt + l15) * 512 + j0 + ks2 * 32 + 8 * l4);

    // ---- online softmax (rows r = 4*l4+e, reduce across 16 l15 lanes) ----
#pragma unroll
    for (int e = 0; e < 4; ++e) {
      float tmax = fmaxf(fmaxf(x[0][e], x[1][e]), fmaxf(x[2][e], x[3][e]));
      tmax = fmaxf(tmax, __shfl_xor(tmax, 1));
      tmax = fmaxf(tmax, __shfl_xor(tmax, 2));
      tmax = fmaxf(tmax, __shfl_xor(tmax, 4));
      tmax = fmaxf(tmax, __shfl_xor(tmax, 8));
      float mn = fmaxf(m[e], tmax);
      float sc = __expf(m[e] - mn);
      float p0 = __expf(x[0][e] - mn);
      float p1 = __expf(x[1][e] - mn);
      float p2 = __expf(x[2][e] - mn);
      float p3 = __expf(x[3][e] - mn);
      float ls = (p0 + p1) + (p2 + p3);
      ls += __shfl_xor(ls, 1);
      ls += __shfl_xor(ls, 2);
      ls += __shfl_xor(ls, 4);
      ls += __shfl_xor(ls, 8);
      lsum[e] = lsum[e] * sc + ls;
      m[e] = mn;
#pragma unroll
      for (int dt = 0; dt < 8; ++dt) pv[dt][e] *= sc;
      int r = 4 * l4 + e;
      pbuf[jq][r][0 + l15] = __builtin_bit_cast(u16, (_Float16)p0);
      pbuf[jq][r][16 + l15] = __builtin_bit_cast(u16, (_Float16)p1);
      pbuf[jq][r][32 + l15] = __builtin_bit_cast(u16, (_Float16)p2);
      pbuf[jq][r][48 + l15] = __builtin_bit_cast(u16, (_Float16)p3);
    }

    asm volatile("s_waitcnt lgkmcnt(0)" ::: "memory");
    __builtin_amdgcn_sched_barrier(0);

    // ---- PV: A = P (row=l15), B = V^T (prefetched) ----
    __builtin_amdgcn_s_setprio(1);
#pragma unroll
    for (int ks2 = 0; ks2 < 2; ++ks2) {
      half8 pa = *(const half8*)((const char*)&pbuf[jq][0][0] + l15 * 144 + ks2 * 64 + l4 * 16);
#pragma unroll
      for (int dt = 0; dt < 8; ++dt)
        pv[dt] = __builtin_amdgcn_mfma_f32_16x16x32_f16(pa, vba[ks2 * 8 + dt], pv[dt], 0, 0, 0);
    }
    __builtin_amdgcn_s_setprio(0);
  }

  // ---- 4-way quarter merge ----
  if (jq != 0) {
#pragma unroll
    for (int dt = 0; dt < 8; ++dt)
#pragma unroll
      for (int e = 0; e < 4; ++e)
        mrg[jq - 1][4 * l4 + e][16 * dt + l15] = pv[dt][e];
    if (l15 == 0) {
#pragma unroll
      for (int e = 0; e < 4; ++e) {
        mml[jq - 1][4 * l4 + e][0] = m[e];
        mml[jq - 1][4 * l4 + e][1] = lsum[e];
      }
    }
  }
  __syncthreads();
  if (jq == 0) {
    float wq[4][3], inv[4];
#pragma unroll
    for (int e = 0; e < 4; ++e) {
      int r = 4 * l4 + e;
      float M = m[e];
#pragma unroll
      for (int q = 0; q < 3; ++q) M = fmaxf(M, mml[q][r][0]);
      float w0 = __expf(m[e] - M);
      float L = lsum[e] * w0;
#pragma unroll
      for (int q = 0; q < 3; ++q) {
        wq[e][q] = __expf(mml[q][r][0] - M);
        L += mml[q][r][1] * wq[e][q];
      }
      inv[e] = 1.0f / L;
      wq[e][0] *= inv[e]; wq[e][1] *= inv[e]; wq[e][2] *= inv[e];
      inv[e] *= w0;  // weight for own pv
    }
#pragma unroll
    for (int dt = 0; dt < 8; ++dt)
#pragma unroll
      for (int e = 0; e < 4; ++e) {
        int r = 4 * l4 + e;
        float o = pv[dt][e] * inv[e];
#pragma unroll
        for (int q = 0; q < 3; ++q) o += mrg[q][r][16 * dt + l15] * wq[e][q];
        out[((size_t)b * 512 + i0r + r) * 128 + 16 * dt + l15] = o;
      }
  }
}

extern "C" void kernel_launch(void* const* d_in, const int* in_sizes, int n_in,
                              void* d_out, int out_size, void* d_ws, size_t ws_size,
                              hipStream_t stream) {
  const float* hl = (const float*)d_in[0];
  const float* ht = (const float*)d_in[1];
  const float* ie = (const float*)d_in[2];
  const float* h  = (const float*)d_in[3];
  const int* adj  = (const int*)d_in[4];
  const float* wd = (const float*)d_in[5];
  const float* a0 = (const float*)d_in[6];
  const float* a1 = (const float*)d_in[7];
  const float* a2 = (const float*)d_in[8];
  const float* a3 = (const float*)d_in[9];

  // ws layout (~16.6 MB)
  float* hds  = (float*)d_ws;                   // 32 KB
  float* s    = (float*)((char*)d_ws + 32768);  // [4][64][512] = 512 KB
  u16* h16    = (u16*)((char*)d_ws + 557056);   // 8 MB
  u16* h16T   = (u16*)((char*)d_ws + 8945664);  // 8 MB
  float* o    = (float*)d_out;

  k_hds<<<64, 256, 0, stream>>>(hl, ht, ie, wd, hds);
  k_prep<<<512, 256, 0, stream>>>(h, hds, a0, a1, a2, a3, s, h16, h16T);
  k_attn<<<2048, 256, 0, stream>>>(h16, h16T, s, adj, a0, a1, a2, a3, o);
}

// Round 15
// 107.825 us; speedup vs baseline: 2.0935x; 1.0032x over previous
//
#include <hip/hip_runtime.h>
#include <hip/hip_bf16.h>
#include <hip/hip_fp16.h>

typedef _Float16 half8 __attribute__((ext_vector_type(8)));
typedef float floatx4 __attribute__((ext_vector_type(4)));
typedef unsigned short u16;
typedef unsigned int u32;
typedef unsigned long long u64;

#define LEAKY 0.2f
#define MASKV -9.0e15f

// ---------------- Kernel A: h_ds[b][d] = (mean of 150 rows) @ wd ----------------
__global__ __launch_bounds__(256) void k_hds(const float* __restrict__ hl,
                                             const float* __restrict__ ht,
                                             const float* __restrict__ ie,
                                             const float* __restrict__ wd,
                                             float* __restrict__ hds) {
  int b = blockIdx.x, tid = threadIdx.x;
  int d = tid & 127, hh = tid >> 7;
  __shared__ float pa_[2][128];
  __shared__ float ml[128];
  __shared__ float pb_[2][128];
  const size_t base = (size_t)b * 50 * 128 + d;
  float acc = 0.f;
  for (int r = hh * 25; r < hh * 25 + 25; ++r) {
    size_t o = base + (size_t)r * 128;
    acc += hl[o] + ht[o] + ie[o];
  }
  pa_[hh][d] = acc;
  __syncthreads();
  if (hh == 0) ml[d] = (pa_[0][d] + pa_[1][d]) * (1.0f / 150.0f);
  __syncthreads();
  float o = 0.f;
  for (int k = hh * 64; k < hh * 64 + 64; ++k) o = fmaf(ml[k], wd[k * 128 + d], o);
  pb_[hh][d] = o;
  __syncthreads();
  if (hh == 0) hds[b * 128 + d] = pb_[0][d] + pb_[1][d];
}

// ---------------- Kernel B: s[w][b][i], h16[b][i][d], h16T[b][d][i] ----------------
__global__ __launch_bounds__(256) void k_prep(const float* __restrict__ h,
                                              const float* __restrict__ hds,
                                              const float* __restrict__ a0,
                                              const float* __restrict__ a1,
                                              const float* __restrict__ a2,
                                              const float* __restrict__ a3,
                                              float* __restrict__ s,
                                              u16* __restrict__ h16,
                                              u16* __restrict__ h16T) {
  int b = blockIdx.x >> 3, i0 = (blockIdx.x & 7) * 64;
  int tid = threadIdx.x, w = tid >> 6, l = tid & 63;
  __shared__ u16 tile[64][130];
  int d0 = 2 * l;
  float2 hd2 = *(const float2*)(hds + b * 128 + d0);
  float2 av0 = *(const float2*)(a0 + d0);
  float2 av1 = *(const float2*)(a1 + d0);
  float2 av2 = *(const float2*)(a2 + d0);
  float2 av3 = *(const float2*)(a3 + d0);
  for (int rr = 0; rr < 16; ++rr) {
    int il = rr * 4 + w;
    size_t row = (size_t)b * 512 + i0 + il;
    float2 hv = *(const float2*)(h + row * 128 + d0);
    _Float16 f0 = (_Float16)hv.x, f1 = (_Float16)hv.y;
    u16 u0 = __builtin_bit_cast(u16, f0), u1 = __builtin_bit_cast(u16, f1);
    tile[il][d0] = u0;
    tile[il][d0 + 1] = u1;
    *(u32*)(h16 + row * 128 + d0) = (u32)u0 | ((u32)u1 << 16);
    float t0 = hv.x * hd2.x, t1 = hv.y * hd2.y;
    float p0 = t0 * av0.x + t1 * av0.y;
    float p1 = t0 * av1.x + t1 * av1.y;
    float p2 = t0 * av2.x + t1 * av2.y;
    float p3 = t0 * av3.x + t1 * av3.y;
    for (int off = 32; off >= 1; off >>= 1) {
      p0 += __shfl_xor(p0, off);
      p1 += __shfl_xor(p1, off);
      p2 += __shfl_xor(p2, off);
      p3 += __shfl_xor(p3, off);
    }
    if (l < 4) {
      float pw = (l == 0) ? p0 : (l == 1) ? p1 : (l == 2) ? p2 : p3;
      s[((size_t)l * 64 + b) * 512 + i0 + il] = pw;
    }
  }
  __syncthreads();
  int d = tid >> 1, hf = tid & 1;
  u32 wds[16];
#pragma unroll
  for (int k = 0; k < 16; ++k) {
    u32 lo = tile[32 * hf + 2 * k][d];
    u32 hi = tile[32 * hf + 2 * k + 1][d];
    wds[k] = lo | (hi << 16);
  }
  uint4* dst = (uint4*)(h16T + ((size_t)b * 128 + d) * 512 + i0 + 32 * hf);
  dst[0] = make_uint4(wds[0], wds[1], wds[2], wds[3]);
  dst[1] = make_uint4(wds[4], wds[5], wds[6], wds[7]);
  dst[2] = make_uint4(wds[8], wds[9], wds[10], wds[11]);
  dst[3] = make_uint4(wds[12], wds[13], wds[14], wds[15]);
}

// ---------------- Kernel C: independent-wave fused attention ----------------
// Block = 4 waves, 16-row i-tile; wave jq owns j-quarter (128 j's = 2 t-bodies).
// R15: explicit cross-t K-prefetch — kfa(t=1) issued after t=0's QK, in flight
// under vba+softmax+PV. si re-read from LDS (frees 16 regs). (256,2), no spill.
__global__ __launch_bounds__(256, 2) void k_attn(const u16* __restrict__ h16,
                                                 const u16* __restrict__ h16T,
                                                 const float* __restrict__ s,
                                                 const int* __restrict__ adj,
                                                 const float* __restrict__ a0,
                                                 const float* __restrict__ a1,
                                                 const float* __restrict__ a2,
                                                 const float* __restrict__ a3,
                                                 float* __restrict__ out) {
  int bid = blockIdx.x;
  int wg = (bid & 7) * 256 + (bid >> 3);  // XCD swizzle (2048 % 8 == 0, bijective)
  int b = wg >> 5, i0r = (wg & 31) * 16;
  int tid = threadIdx.x, jq = tid >> 6, l = tid & 63;
  int l15 = l & 15, l4 = l >> 4;

  __shared__ u16 a16[4][128];        // a vectors, f16
  __shared__ float s_lds[4][512];    // per-head s row for this b (8 KB)
  __shared__ u16 pbuf[4][16][72];    // per-wave P relayout
  __shared__ float mrg[3][16][132];  // quarter-merge pv (jq=1..3)
  __shared__ float mml[3][16][2];    // quarter-merge m,l

  const size_t hb16 = (size_t)b * 512 * 128;
  const size_t hTb = (size_t)b * 128 * 512;

  // ---- prologue: HBM-cold adj loads first (both t-bodies) ----
  u32 ct[2][4];
#pragma unroll
  for (int t = 0; t < 2; ++t)
#pragma unroll
    for (int e = 0; e < 4; ++e) {
      u32 v = 0;
      const int* ap = adj + ((size_t)(b * 512 + i0r + 4 * l4 + e)) * 512 + jq * 128 + t * 64 + l15;
#pragma unroll
      for (int C = 0; C < 4; ++C) {
        int av = ap[16 * C];
        if (av > 0) v |= (1u << (4 * (av - 1) + C));
      }
      ct[t][e] = v;
    }

  // A-side h fragments: row = l15, k = ks*32+8*l4+e
  half8 hf[4];
#pragma unroll
  for (int ks = 0; ks < 4; ++ks)
    hf[ks] = *(const half8*)(h16 + hb16 + (size_t)(i0r + l15) * 128 + ks * 32 + 8 * l4);

  // cooperative staging: a vectors (f16) + s rows (f32) into LDS
  if (tid < 128) {
    a16[0][tid] = __builtin_bit_cast(u16, (_Float16)a0[tid]);
    a16[1][tid] = __builtin_bit_cast(u16, (_Float16)a1[tid]);
    a16[2][tid] = __builtin_bit_cast(u16, (_Float16)a2[tid]);
    a16[3][tid] = __builtin_bit_cast(u16, (_Float16)a3[tid]);
  }
#pragma unroll
  for (int p = 0; p < 2; ++p) {
    int cid = p * 256 + tid;  // [0,512)
    int hd = cid >> 7, i4 = (cid & 127) * 4;
    *(float4*)&s_lds[hd][i4] = *(const float4*)(s + ((size_t)hd * 64 + b) * 512 + i4);
  }
  __syncthreads();

  float m[4], lsum[4];
#pragma unroll
  for (int e = 0; e < 4; ++e) { m[e] = MASKV; lsum[e] = 0.f; }
  floatx4 pv[8];
#pragma unroll
  for (int dt = 0; dt < 8; ++dt) pv[dt] = (floatx4){0.f, 0.f, 0.f, 0.f};

  // ---- helpers (inlined; all literal args -> static indexing) ----
  auto load_kfa = [&](int j0, half8* dst) {
#pragma unroll
    for (int ks = 0; ks < 4; ++ks)
#pragma unroll
      for (int C = 0; C < 4; ++C)
        dst[ks * 4 + C] = *(const half8*)(h16 + hb16 + (size_t)(j0 + 16 * C + l15) * 128 + ks * 32 + 8 * l4);
  };
  auto load_vba = [&](int j0, half8* dst) {
#pragma unroll
    for (int ks2 = 0; ks2 < 2; ++ks2)
#pragma unroll
      for (int dt = 0; dt < 8; ++dt)
        dst[ks2 * 8 + dt] = *(const half8*)(h16T + hTb + (size_t)(16 * dt + l15) * 512 + j0 + ks2 * 32 + 8 * l4);
  };
  auto qk_select = [&](const u32* ctv, const half8* kfa, int j0, float x[4][4]) {
#pragma unroll
    for (int C = 0; C < 4; ++C)
#pragma unroll
      for (int e = 0; e < 4; ++e) x[C][e] = MASKV;
#pragma unroll
    for (int hd = 0; hd < 4; ++hd) {
      float sjh[4], sih[4];
#pragma unroll
      for (int C = 0; C < 4; ++C) sjh[C] = s_lds[hd][j0 + 16 * C + l15];
#pragma unroll
      for (int e = 0; e < 4; ++e) sih[e] = s_lds[hd][i0r + 4 * l4 + e];
      floatx4 qk[4];
#pragma unroll
      for (int C = 0; C < 4; ++C) qk[C] = (floatx4){0.f, 0.f, 0.f, 0.f};
      __builtin_amdgcn_s_setprio(1);
#pragma unroll
      for (int ks = 0; ks < 4; ++ks) {
        half8 af = *(const half8*)&a16[hd][ks * 32 + 8 * l4];
        half8 q = hf[ks] * af;
#pragma unroll
        for (int C = 0; C < 4; ++C)
          qk[C] = __builtin_amdgcn_mfma_f32_16x16x32_f16(q, kfa[ks * 4 + C], qk[C], 0, 0, 0);
      }
      __builtin_amdgcn_s_setprio(0);
#pragma unroll
      for (int e = 0; e < 4; ++e) {
#pragma unroll
        for (int C = 0; C < 4; ++C) {
          if ((ctv[e] >> (4 * hd + C)) & 1) {
            float v = qk[C][e] + sih[e] + sjh[C];
            x[C][e] = (v > 0.f) ? v : LEAKY * v;
          }
        }
      }
    }
  };
  auto softmax_store = [&](float x[4][4]) {
#pragma unroll
    for (int e = 0; e < 4; ++e) {
      float tmax = fmaxf(fmaxf(x[0][e], x[1][e]), fmaxf(x[2][e], x[3][e]));
      tmax = fmaxf(tmax, __shfl_xor(tmax, 1));
      tmax = fmaxf(tmax, __shfl_xor(tmax, 2));
      tmax = fmaxf(tmax, __shfl_xor(tmax, 4));
      tmax = fmaxf(tmax, __shfl_xor(tmax, 8));
      float mn = fmaxf(m[e], tmax);
      float sc = __expf(m[e] - mn);
      float p0 = __expf(x[0][e] - mn);
      float p1 = __expf(x[1][e] - mn);
      float p2 = __expf(x[2][e] - mn);
      float p3 = __expf(x[3][e] - mn);
      float ls = (p0 + p1) + (p2 + p3);
      ls += __shfl_xor(ls, 1);
      ls += __shfl_xor(ls, 2);
      ls += __shfl_xor(ls, 4);
      ls += __shfl_xor(ls, 8);
      lsum[e] = lsum[e] * sc + ls;
      m[e] = mn;
#pragma unroll
      for (int dt = 0; dt < 8; ++dt) pv[dt][e] *= sc;
      int r = 4 * l4 + e;
      pbuf[jq][r][0 + l15] = __builtin_bit_cast(u16, (_Float16)p0);
      pbuf[jq][r][16 + l15] = __builtin_bit_cast(u16, (_Float16)p1);
      pbuf[jq][r][32 + l15] = __builtin_bit_cast(u16, (_Float16)p2);
      pbuf[jq][r][48 + l15] = __builtin_bit_cast(u16, (_Float16)p3);
    }
  };
  auto pv_mfma = [&](const half8* vba) {
    __builtin_amdgcn_s_setprio(1);
#pragma unroll
    for (int ks2 = 0; ks2 < 2; ++ks2) {
      half8 pa = *(const half8*)((const char*)&pbuf[jq][0][0] + l15 * 144 + ks2 * 64 + l4 * 16);
#pragma unroll
      for (int dt = 0; dt < 8; ++dt)
        pv[dt] = __builtin_amdgcn_mfma_f32_16x16x32_f16(pa, vba[ks2 * 8 + dt], pv[dt], 0, 0, 0);
    }
    __builtin_amdgcn_s_setprio(0);
  };

  const int j0a = jq * 128, j0b = jq * 128 + 64;
  half8 kfa0[16], kfa1[16], vba[16];
  float x[4][4];

  // ---------- t = 0 ----------
  load_kfa(j0a, kfa0);
  qk_select(&ct[0][0], kfa0, j0a, x);
  load_vba(j0a, vba);   // needed first (PV0)
  load_kfa(j0b, kfa1);  // prefetch t=1 K; stays in flight under softmax+PV
  softmax_store(x);
  asm volatile("s_waitcnt lgkmcnt(0)" ::: "memory");
  __builtin_amdgcn_sched_barrier(0);
  pv_mfma(vba);

  // ---------- t = 1 ----------
  qk_select(&ct[1][0], kfa1, j0b, x);
  load_vba(j0b, vba);
  softmax_store(x);
  asm volatile("s_waitcnt lgkmcnt(0)" ::: "memory");
  __builtin_amdgcn_sched_barrier(0);
  pv_mfma(vba);

  // ---- 4-way quarter merge ----
  if (jq != 0) {
#pragma unroll
    for (int dt = 0; dt < 8; ++dt)
#pragma unroll
      for (int e = 0; e < 4; ++e)
        mrg[jq - 1][4 * l4 + e][16 * dt + l15] = pv[dt][e];
    if (l15 == 0) {
#pragma unroll
      for (int e = 0; e < 4; ++e) {
        mml[jq - 1][4 * l4 + e][0] = m[e];
        mml[jq - 1][4 * l4 + e][1] = lsum[e];
      }
    }
  }
  __syncthreads();
  if (jq == 0) {
    float wq[4][3], inv[4];
#pragma unroll
    for (int e = 0; e < 4; ++e) {
      int r = 4 * l4 + e;
      float M = m[e];
#pragma unroll
      for (int q = 0; q < 3; ++q) M = fmaxf(M, mml[q][r][0]);
      float w0 = __expf(m[e] - M);
      float L = lsum[e] * w0;
#pragma unroll
      for (int q = 0; q < 3; ++q) {
        wq[e][q] = __expf(mml[q][r][0] - M);
        L += mml[q][r][1] * wq[e][q];
      }
      inv[e] = 1.0f / L;
      wq[e][0] *= inv[e]; wq[e][1] *= inv[e]; wq[e][2] *= inv[e];
      inv[e] *= w0;  // weight for own pv
    }
#pragma unroll
    for (int dt = 0; dt < 8; ++dt)
#pragma unroll
      for (int e = 0; e < 4; ++e) {
        int r = 4 * l4 + e;
        float o = pv[dt][e] * inv[e];
#pragma unroll
        for (int q = 0; q < 3; ++q) o += mrg[q][r][16 * dt + l15] * wq[e][q];
        out[((size_t)b * 512 + i0r + r) * 128 + 16 * dt + l15] = o;
      }
  }
}

extern "C" void kernel_launch(void* const* d_in, const int* in_sizes, int n_in,
                              void* d_out, int out_size, void* d_ws, size_t ws_size,
                              hipStream_t stream) {
  const float* hl = (const float*)d_in[0];
  const float* ht = (const float*)d_in[1];
  const float* ie = (const float*)d_in[2];
  const float* h  = (const float*)d_in[3];
  const int* adj  = (const int*)d_in[4];
  const float* wd = (const float*)d_in[5];
  const float* a0 = (const float*)d_in[6];
  const float* a1 = (const float*)d_in[7];
  const float* a2 = (const float*)d_in[8];
  const float* a3 = (const float*)d_in[9];

  // ws layout (~16.6 MB)
  float* hds  = (float*)d_ws;                   // 32 KB
  float* s    = (float*)((char*)d_ws + 32768);  // [4][64][512] = 512 KB
  u16* h16    = (u16*)((char*)d_ws + 557056);   // 8 MB
  u16* h16T   = (u16*)((char*)d_ws + 8945664);  // 8 MB
  float* o    = (float*)d_out;

  k_hds<<<64, 256, 0, stream>>>(hl, ht, ie, wd, hds);
  k_prep<<<512, 256, 0, stream>>>(h, hds, a0, a1, a2, a3, s, h16, h16T);
  k_attn<<<2048, 256, 0, stream>>>(h16, h16T, s, adj, a0, a1, a2, a3, o);
}